// Round 2
// baseline (479.501 us; speedup 1.0000x reference)
//
#include <hip/hip_runtime.h>
#include <hip/hip_bf16.h>

// ScaledDotProductAttention: N=M=8192, DK=DV=256, fp32 in/out.
// R2: bf16 MFMA flash attention, NO K/V LDS staging (L2-resident, read
// direct from global), barrier-free main loop. 256 blocks x 768 threads
// (12 waves = 3 waves/SIMD): wave = (q-tile of 16 rows [qt=w&1], KV chunk
// [ck=w>>1, 6-way split]). KVSTEP=64. Online softmax per wave; 6-round
// LDS merge at the end.

typedef __attribute__((ext_vector_type(4))) float floatx4;
typedef __attribute__((ext_vector_type(8))) short short8;

union S8u { short8 v; unsigned short u[8]; };

__device__ __forceinline__ unsigned short f2bf(float f) {
    unsigned int u = __builtin_bit_cast(unsigned int, f);
    unsigned int r = u + 0x7fffu + ((u >> 16) & 1u);   // RNE
    return (unsigned short)(r >> 16);
}

// ---------------- conversion kernels ----------------

__global__ void cvt_bf16_kernel(const float* __restrict__ in,
                                unsigned short* __restrict__ out,
                                float scale, int n8) {
    int i = blockIdx.x * blockDim.x + threadIdx.x;
    if (i >= n8) return;
    const float4* p = reinterpret_cast<const float4*>(in) + (size_t)i * 2;
    float4 a = p[0], b = p[1];
    S8u r;
    r.u[0] = f2bf(a.x * scale); r.u[1] = f2bf(a.y * scale);
    r.u[2] = f2bf(a.z * scale); r.u[3] = f2bf(a.w * scale);
    r.u[4] = f2bf(b.x * scale); r.u[5] = f2bf(b.y * scale);
    r.u[6] = f2bf(b.z * scale); r.u[7] = f2bf(b.w * scale);
    *reinterpret_cast<short8*>(out + (size_t)i * 8) = r.v;
}

// V [8192][256] f32 -> Vt [256][8192] bf16, 64x64 tiles
__global__ void transpose_v_kernel(const float* __restrict__ V,
                                   unsigned short* __restrict__ Vt) {
    __shared__ unsigned short T[64][72];
    const int kv0 = blockIdx.x * 64;
    const int v0  = blockIdx.y * 64;
    const int tid = threadIdx.x;           // 256
#pragma unroll
    for (int it = 0; it < 4; ++it) {
        int flat = it * 256 + tid;
        int r  = flat >> 4;
        int c4 = (flat & 15) * 4;
        float4 f = *reinterpret_cast<const float4*>(
            V + (size_t)(kv0 + r) * 256 + v0 + c4);
        T[c4 + 0][r] = f2bf(f.x);
        T[c4 + 1][r] = f2bf(f.y);
        T[c4 + 2][r] = f2bf(f.z);
        T[c4 + 3][r] = f2bf(f.w);
    }
    __syncthreads();
#pragma unroll
    for (int it = 0; it < 2; ++it) {
        int flat = it * 256 + tid;
        int r  = flat >> 3;
        int c8 = (flat & 7) * 8;
        short8 v8 = *reinterpret_cast<const short8*>(&T[r][c8]);
        *reinterpret_cast<short8*>(Vt + (size_t)(v0 + r) * 8192 + kv0 + c8) = v8;
    }
}

// ---------------- main attention kernel ----------------

#define PSTRIDE 72   // P_lds row stride (elems), 144B (16B-aligned)

__global__ __launch_bounds__(768, 3)
void attn_kernel(const unsigned short* __restrict__ Qb,   // [8192][256], pre-scaled
                 const unsigned short* __restrict__ Kb,   // [8192][256]
                 const unsigned short* __restrict__ Vt,   // [256][8192]
                 float* __restrict__ out) {               // [8192][256]
    // P_lds [12][16][72] (27648 B) overlaps merge buffers (33152 B); a
    // __syncthreads separates last P use from first merge write.
    __shared__ __align__(16) char smem[33152];
    unsigned short* P_all = reinterpret_cast<unsigned short*>(smem);
    float* bufO  = reinterpret_cast<float*>(smem);          // [2][16][257]
    float* bufML = reinterpret_cast<float*>(smem + 32896);  // [2][16][2]

    const int tid  = threadIdx.x;
    const int lane = tid & 63;
    const int w    = tid >> 6;      // 0..11
    const int qt   = w & 1;         // q sub-tile
    const int ck   = w >> 1;        // KV chunk 0..5
    const int l15  = lane & 15;
    const int lg   = lane >> 4;     // 0..3
    const int qrow0 = blockIdx.x * 32 + qt * 16;

    // Q fragments: row qrow0+l15, d = ss*32 + lg*8 + e
    short8 qf[8];
    {
        const unsigned short* qp = Qb + (size_t)(qrow0 + l15) * 256 + lg * 8;
#pragma unroll
        for (int ss = 0; ss < 8; ++ss)
            qf[ss] = *reinterpret_cast<const short8*>(qp + ss * 32);
    }

    floatx4 o[16];
#pragma unroll
    for (int v = 0; v < 16; ++v) o[v] = floatx4{0.f, 0.f, 0.f, 0.f};
    float m_run[4], l_run[4];
#pragma unroll
    for (int r = 0; r < 4; ++r) { m_run[r] = -1e30f; l_run[r] = 0.f; }

    // chunk tile range: 128 tiles of 64, split 22,22,21,21,21,21
    const int tbeg = 21 * ck + (ck < 2 ? ck : 2);
    const int tend = tbeg + (ck < 2 ? 22 : 21);

    unsigned short* Pw = P_all + w * (16 * PSTRIDE);

    for (int t = tbeg; t < tend; ++t) {
        const int kv0 = t * 64;
        // ---- QK^T: S[16q x 64kv], B-frags direct from global K ----
        floatx4 s[4];
#pragma unroll
        for (int tt = 0; tt < 4; ++tt) s[tt] = floatx4{0.f, 0.f, 0.f, 0.f};
        const unsigned short* kbase = Kb + (size_t)(kv0 + l15) * 256 + lg * 8;
#pragma unroll
        for (int ss = 0; ss < 8; ++ss) {
#pragma unroll
            for (int tt = 0; tt < 4; ++tt) {
                short8 b = *reinterpret_cast<const short8*>(
                    kbase + tt * (16 * 256) + ss * 32);
                s[tt] = __builtin_amdgcn_mfma_f32_16x16x32_bf16(qf[ss], b, s[tt], 0, 0, 0);
            }
        }
        // ---- online softmax: row = lg*4+r, col = tt*16+l15 ----
        float al[4];
#pragma unroll
        for (int r = 0; r < 4; ++r) {
            float v = fmaxf(fmaxf(s[0][r], s[1][r]), fmaxf(s[2][r], s[3][r]));
            v = fmaxf(v, __shfl_xor(v, 8));
            v = fmaxf(v, __shfl_xor(v, 4));
            v = fmaxf(v, __shfl_xor(v, 2));
            v = fmaxf(v, __shfl_xor(v, 1));
            float mn = fmaxf(m_run[r], v);
            al[r] = __expf(m_run[r] - mn);
            m_run[r] = mn;
            float rs = 0.f;
#pragma unroll
            for (int tt = 0; tt < 4; ++tt) {
                float p = __expf(s[tt][r] - mn);
                s[tt][r] = p;
                rs += p;
            }
            rs += __shfl_xor(rs, 8);
            rs += __shfl_xor(rs, 4);
            rs += __shfl_xor(rs, 2);
            rs += __shfl_xor(rs, 1);
            l_run[r] = l_run[r] * al[r] + rs;
        }
#pragma unroll
        for (int v = 0; v < 16; ++v) {
#pragma unroll
            for (int r = 0; r < 4; ++r) o[v][r] *= al[r];
        }
        // ---- P -> wave-private LDS (transpose to A-frag layout) ----
#pragma unroll
        for (int tt = 0; tt < 4; ++tt) {
#pragma unroll
            for (int r = 0; r < 4; ++r)
                Pw[(lg * 4 + r) * PSTRIDE + tt * 16 + l15] = f2bf(s[tt][r]);
        }
        short8 pf0 = *reinterpret_cast<const short8*>(&Pw[l15 * PSTRIDE + lg * 8]);
        short8 pf1 = *reinterpret_cast<const short8*>(&Pw[l15 * PSTRIDE + 32 + lg * 8]);
        // ---- PV: O += P[16x64] * V[64x256], B-frags direct from global Vt ----
        const unsigned short* vbase = Vt + (size_t)l15 * 8192 + kv0 + lg * 8;
#pragma unroll
        for (int v = 0; v < 16; ++v) {
            const unsigned short* vp = vbase + (size_t)v * (16 * 8192);
            short8 b0 = *reinterpret_cast<const short8*>(vp);
            short8 b1 = *reinterpret_cast<const short8*>(vp + 32);
            o[v] = __builtin_amdgcn_mfma_f32_16x16x32_bf16(pf0, b0, o[v], 0, 0, 0);
            o[v] = __builtin_amdgcn_mfma_f32_16x16x32_bf16(pf1, b1, o[v], 0, 0, 0);
        }
    }

    __syncthreads();   // all waves done with P_lds before merge buffers reuse smem

    // ---- 6-round sequential merge per q-tile (ck order), final writes out ----
    for (int round = 0; round < 6; ++round) {
        if (ck == round) {
            float* bO = bufO + qt * (16 * 257);
            float* bM = bufML + qt * 32;
            if (round == 0) {
#pragma unroll
                for (int r = 0; r < 4; ++r) {
                    int row = lg * 4 + r;
#pragma unroll
                    for (int v = 0; v < 16; ++v)
                        bO[row * 257 + v * 16 + l15] = o[v][r];
                }
                if (l15 == 0) {
#pragma unroll
                    for (int r = 0; r < 4; ++r) {
                        bM[(lg * 4 + r) * 2 + 0] = m_run[r];
                        bM[(lg * 4 + r) * 2 + 1] = l_run[r];
                    }
                }
            } else if (round < 5) {
#pragma unroll
                for (int r = 0; r < 4; ++r) {
                    int row = lg * 4 + r;
                    float mB = bM[row * 2 + 0], lB = bM[row * 2 + 1];
                    float m  = fmaxf(m_run[r], mB);
                    float aB = __expf(mB - m);
                    float aC = __expf(m_run[r] - m);
#pragma unroll
                    for (int v = 0; v < 16; ++v) {
                        float* p = &bO[row * 257 + v * 16 + l15];
                        *p = *p * aB + o[v][r] * aC;
                    }
                    if (l15 == 0) {
                        bM[row * 2 + 0] = m;
                        bM[row * 2 + 1] = lB * aB + l_run[r] * aC;
                    }
                }
            } else {
#pragma unroll
                for (int r = 0; r < 4; ++r) {
                    int row = lg * 4 + r;
                    float mB = bM[row * 2 + 0], lB = bM[row * 2 + 1];
                    float m  = fmaxf(m_run[r], mB);
                    float aB = __expf(mB - m);
                    float aC = __expf(m_run[r] - m);
                    float linv = 1.0f / (lB * aB + l_run[r] * aC);
#pragma unroll
                    for (int v = 0; v < 16; ++v) {
                        float val = (bO[row * 257 + v * 16 + l15] * aB + o[v][r] * aC) * linv;
                        out[(size_t)(qrow0 + row) * 256 + v * 16 + l15] = val;
                    }
                }
            }
        }
        __syncthreads();
    }
}

// ---------------- launcher ----------------

extern "C" void kernel_launch(void* const* d_in, const int* in_sizes, int n_in,
                              void* d_out, int out_size, void* d_ws, size_t ws_size,
                              hipStream_t stream) {
    const float* Q = (const float*)d_in[0];
    const float* K = (const float*)d_in[1];
    const float* V = (const float*)d_in[2];
    float* out = (float*)d_out;

    unsigned short* Qb = (unsigned short*)d_ws;            // 4 MB
    unsigned short* Kb = Qb + (size_t)8192 * 256;          // 4 MB
    unsigned short* Vt = Kb + (size_t)8192 * 256;          // 4 MB

    const int n8 = 8192 * 256 / 8;  // 262144
    cvt_bf16_kernel<<<n8 / 256, 256, 0, stream>>>(Q, Qb, 0.0625f, n8);
    cvt_bf16_kernel<<<n8 / 256, 256, 0, stream>>>(K, Kb, 1.0f, n8);
    transpose_v_kernel<<<dim3(128, 4), 256, 0, stream>>>(V, Vt);
    attn_kernel<<<256, 768, 0, stream>>>(Qb, Kb, Vt, out);
}

// Round 3
// 142.896 us; speedup vs baseline: 3.3556x; 3.3556x over previous
//
#include <hip/hip_runtime.h>
#include <hip/hip_bf16.h>

// ScaledDotProductAttention N=M=8192, DK=DV=256, fp32 io.
// R3: HK-style flash attn. 32x32x16 bf16 MFMA, swapped QK^T (S^T = K x Q^T)
// so P is lane-local (no cross-lane softmax, no P LDS round trip).
// 8 waves x 32 q-rows = 256-row q-block; grid = 32 q-blocks x NG kv-groups.
// KV tile 64 double-buffered in LDS (128KB) via global_load_lds(16B) with
// pre-swizzled global source + XOR-swizzled reads. One barrier per tile.
// Per-group unnormalized partials merged by a second kernel.

typedef __attribute__((ext_vector_type(16))) float floatx16;
typedef __attribute__((ext_vector_type(8)))  short short8;

union S8u { short8 v; unsigned short u[8]; };

__device__ __forceinline__ unsigned short f2bf(float f) {
    unsigned int u = __builtin_bit_cast(unsigned int, f);
    unsigned int r = u + 0x7fffu + ((u >> 16) & 1u);   // RNE
    return (unsigned short)(r >> 16);
}

__device__ __forceinline__ unsigned cvtpk_bf16(float lo, float hi) {
    unsigned r;
    asm("v_cvt_pk_bf16_f32 %0, %1, %2" : "=v"(r) : "v"(lo), "v"(hi));
    return r;
}

__device__ __forceinline__ void gload16(const void* g, void* l) {
    __builtin_amdgcn_global_load_lds(
        (const __attribute__((address_space(1))) unsigned int*)g,
        (__attribute__((address_space(3))) unsigned int*)l, 16, 0, 0);
}

// ---------------- conversion kernels ----------------

__global__ void cvt_bf16_kernel(const float* __restrict__ in,
                                unsigned short* __restrict__ out,
                                float scale, int n8) {
    int i = blockIdx.x * blockDim.x + threadIdx.x;
    if (i >= n8) return;
    const float4* p = reinterpret_cast<const float4*>(in) + (size_t)i * 2;
    float4 a = p[0], b = p[1];
    S8u r;
    r.u[0] = f2bf(a.x * scale); r.u[1] = f2bf(a.y * scale);
    r.u[2] = f2bf(a.z * scale); r.u[3] = f2bf(a.w * scale);
    r.u[4] = f2bf(b.x * scale); r.u[5] = f2bf(b.y * scale);
    r.u[6] = f2bf(b.z * scale); r.u[7] = f2bf(b.w * scale);
    *reinterpret_cast<short8*>(out + (size_t)i * 8) = r.v;
}

// V [8192][256] f32 -> Vt [256][8192] bf16
__global__ void transpose_v_kernel(const float* __restrict__ V,
                                   unsigned short* __restrict__ Vt) {
    __shared__ unsigned short T[64][72];
    const int kv0 = blockIdx.x * 64;
    const int v0  = blockIdx.y * 64;
    const int tid = threadIdx.x;           // 256
#pragma unroll
    for (int it = 0; it < 4; ++it) {
        int flat = it * 256 + tid;
        int r  = flat >> 4;
        int c4 = (flat & 15) * 4;
        float4 f = *reinterpret_cast<const float4*>(
            V + (size_t)(kv0 + r) * 256 + v0 + c4);
        T[c4 + 0][r] = f2bf(f.x);
        T[c4 + 1][r] = f2bf(f.y);
        T[c4 + 2][r] = f2bf(f.z);
        T[c4 + 3][r] = f2bf(f.w);
    }
    __syncthreads();
#pragma unroll
    for (int it = 0; it < 2; ++it) {
        int flat = it * 256 + tid;
        int r  = flat >> 3;
        int c8 = (flat & 7) * 8;
        short8 v8 = *reinterpret_cast<const short8*>(&T[r][c8]);
        *reinterpret_cast<short8*>(Vt + (size_t)(v0 + r) * 8192 + kv0 + c8) = v8;
    }
}

// ---------------- main attention kernel ----------------

__global__ __launch_bounds__(512, 2)
void attn_kernel(const unsigned short* __restrict__ Qb,   // [8192][256] prescaled
                 const unsigned short* __restrict__ Kb,   // [8192][256]
                 const unsigned short* __restrict__ VtG,  // [256][8192]
                 float* __restrict__ Opart,               // [NG][8192][256]
                 float* __restrict__ Ml,                  // [NG][8192][2]
                 int kv_span, int gshift) {
    // [buf][ K 32KB | Vt 32KB ]
    __shared__ __align__(16) unsigned char lds[2][65536];

    const int tid  = threadIdx.x;
    const int lane = tid & 63;
    const int w    = tid >> 6;     // 0..7
    const int l31  = lane & 31;
    const int h    = lane >> 5;    // 0/1

    const int ngm1 = (1 << gshift) - 1;
    const int id   = blockIdx.x + 32 * blockIdx.y;
    const int g    = id & ngm1;          // XCD-affine: consecutive ids -> groups
    const int qblk = id >> gshift;       // 0..31
    const int kv_begin = g * kv_span;
    const int tiles = kv_span >> 6;
    const int q0 = qblk * 256 + w * 32;

    // Q as B-fragments: col=q=l31(row of Q), k = d = ds*16 + h*8 + e
    short8 qf[16];
    {
        const unsigned short* qp = Qb + (size_t)(q0 + l31) * 256 + h * 8;
#pragma unroll
        for (int ds = 0; ds < 16; ++ds)
            qf[ds] = *reinterpret_cast<const short8*>(qp + ds * 16);
    }

    floatx16 o[8];
#pragma unroll
    for (int vt = 0; vt < 8; ++vt)
#pragma unroll
        for (int r = 0; r < 16; ++r) o[vt][r] = 0.f;
    float m_run = -1e30f, l_run = 0.f;

    // stage tile kv0 into lds[bufsel]: linear LDS dest, inverse-swizzled src
    auto STAGE = [&](int kv0, int bufsel) {
        unsigned char* kb = &lds[bufsel][0];
        unsigned char* vb = &lds[bufsel][32768];
#pragma unroll
        for (int i = 0; i < 4; ++i) {
            int j = w * 4 + i;   // 0..31, wave-uniform
            {   // K: 64 rows x 512B; chunk j = 2 rows
                int row = j * 2 + (lane >> 5);
                int c   = lane & 31;
                int cs  = c ^ (row & 7);
                gload16(Kb + (size_t)(kv0 + row) * 256 + cs * 8, kb + j * 1024);
            }
            {   // Vt: 256 rows x 128B; chunk j = 8 rows
                int row = j * 8 + (lane >> 3);
                int c   = lane & 7;
                int cs  = c ^ (row & 7);
                gload16(VtG + (size_t)row * 8192 + kv0 + cs * 8, vb + j * 1024);
            }
        }
    };

    STAGE(kv_begin, 0);
    asm volatile("s_waitcnt vmcnt(0)" ::: "memory");
    __syncthreads();

    const int swz = l31 & 7;

    for (int t = 0; t < tiles; ++t) {
        const int cur = t & 1;
        if (t + 1 < tiles) STAGE(kv_begin + (t + 1) * 64, cur ^ 1);

        const unsigned char* kl = &lds[cur][0];
        const unsigned char* vl = &lds[cur][32768];

        // ---- S^T = K x Q^T : s0 = kv 0..31, s1 = kv 32..63 (cols = q) ----
        floatx16 s0, s1;
#pragma unroll
        for (int r = 0; r < 16; ++r) { s0[r] = 0.f; s1[r] = 0.f; }
#pragma unroll
        for (int ds = 0; ds < 16; ++ds) {
            int c0 = (ds * 2 + h) ^ swz;
            short8 a0 = *reinterpret_cast<const short8*>(kl + (size_t)l31 * 512 + c0 * 16);
            short8 a1 = *reinterpret_cast<const short8*>(kl + (size_t)(l31 + 32) * 512 + c0 * 16);
            s0 = __builtin_amdgcn_mfma_f32_32x32x16_bf16(a0, qf[ds], s0, 0, 0, 0);
            s1 = __builtin_amdgcn_mfma_f32_32x32x16_bf16(a1, qf[ds], s1, 0, 0, 0);
        }

        // ---- online softmax, fully in-lane (q = l31; rows split h / h^1) ----
        float mt = s0[0];
#pragma unroll
        for (int r = 1; r < 16; ++r) mt = fmaxf(mt, s0[r]);
#pragma unroll
        for (int r = 0; r < 16; ++r) mt = fmaxf(mt, s1[r]);
        mt = fmaxf(mt, __shfl_xor(mt, 32));
        if (__any(mt > m_run + 8.0f)) {          // defer-max (T13)
            float mnew = fmaxf(m_run, mt);
            float al = __expf(m_run - mnew);
            m_run = mnew;
            l_run *= al;
#pragma unroll
            for (int reg = 0; reg < 16; ++reg) {
                int srcl = ((reg & 3) + 8 * (reg >> 2)) + 4 * h;
                float alr = __shfl(al, srcl);
#pragma unroll
                for (int vt = 0; vt < 8; ++vt) o[vt][reg] *= alr;
            }
        }
        float lt = 0.f;
#pragma unroll
        for (int r = 0; r < 16; ++r) { float p = __expf(s0[r] - m_run); s0[r] = p; lt += p; }
#pragma unroll
        for (int r = 0; r < 16; ++r) { float p = __expf(s1[r] - m_run); s1[r] = p; lt += p; }
        lt += __shfl_xor(lt, 32);
        l_run += lt;

        // ---- PV: O[32q x 256v] += P[32x64] * V[64x256] ----
        // A-frag (P) per 16-kv step: k = h*8+e; rows 4h+0..3 own regs, rest partner
        auto buildPA = [&](const floatx16& sv, int rbase) -> short8 {
            unsigned cpk0 = cvtpk_bf16(sv[rbase + 0], sv[rbase + 1]);
            unsigned cpk1 = cvtpk_bf16(sv[rbase + 2], sv[rbase + 3]);
            unsigned cpk2 = cvtpk_bf16(sv[rbase + 4], sv[rbase + 5]);
            unsigned cpk3 = cvtpk_bf16(sv[rbase + 6], sv[rbase + 7]);
            unsigned send0 = h ? cpk0 : cpk2;
            unsigned send1 = h ? cpk1 : cpk3;
            unsigned r0 = (unsigned)__shfl_xor((int)send0, 32);
            unsigned r1 = (unsigned)__shfl_xor((int)send1, 32);
            uint4 uu;
            uu.x = h ? r0 : cpk0;
            uu.y = h ? r1 : cpk1;
            uu.z = h ? cpk2 : r0;
            uu.w = h ? cpk3 : r1;
            return __builtin_bit_cast(short8, uu);
        };

#pragma unroll
        for (int kk = 0; kk < 4; ++kk) {
            short8 pa = buildPA((kk < 2) ? s0 : s1, (kk & 1) * 8);
            int cv = (kk * 2 + h) ^ swz;
#pragma unroll
            for (int vt = 0; vt < 8; ++vt) {
                short8 b = *reinterpret_cast<const short8*>(
                    vl + (size_t)(vt * 32 + l31) * 128 + cv * 16);
                o[vt] = __builtin_amdgcn_mfma_f32_32x32x16_bf16(pa, b, o[vt], 0, 0, 0);
            }
        }

        asm volatile("s_waitcnt vmcnt(0)" ::: "memory");
        __syncthreads();
    }

    // ---- epilogue: unnormalized partial + (m,l) ----
    const size_t gq = (size_t)g * 8192;
#pragma unroll
    for (int vt = 0; vt < 8; ++vt) {
#pragma unroll
        for (int reg = 0; reg < 16; ++reg) {
            int row = (reg & 3) + 8 * (reg >> 2) + 4 * h;
            Opart[(gq + q0 + row) * 256 + vt * 32 + l31] = o[vt][reg];
        }
    }
    if (h == 0) {
        size_t idx = (gq + q0 + l31) * 2;
        Ml[idx]     = m_run;
        Ml[idx + 1] = l_run;
    }
}

// ---------------- merge kernel ----------------

__global__ void merge_kernel(const float* __restrict__ Opart,
                             const float* __restrict__ Ml,
                             float* __restrict__ out, int ngroups) {
    int row = blockIdx.x;
    int col = threadIdx.x;
    float m = -1e30f;
    for (int g = 0; g < ngroups; ++g)
        m = fmaxf(m, Ml[((size_t)g * 8192 + row) * 2]);
    float den = 0.f, acc = 0.f;
    for (int g = 0; g < ngroups; ++g) {
        float wg = __expf(Ml[((size_t)g * 8192 + row) * 2] - m);
        den += wg * Ml[((size_t)g * 8192 + row) * 2 + 1];
        acc += wg * Opart[((size_t)g * 8192 + row) * 256 + col];
    }
    out[(size_t)row * 256 + col] = acc / den;
}

// ---------------- launcher ----------------

extern "C" void kernel_launch(void* const* d_in, const int* in_sizes, int n_in,
                              void* d_out, int out_size, void* d_ws, size_t ws_size,
                              hipStream_t stream) {
    const float* Q = (const float*)d_in[0];
    const float* K = (const float*)d_in[1];
    const float* V = (const float*)d_in[2];
    float* out = (float*)d_out;

    unsigned short* Qb = (unsigned short*)d_ws;            // 4 MiB
    unsigned short* Kb = Qb + (size_t)8192 * 256;          // 4 MiB
    unsigned short* Vt = Kb + (size_t)8192 * 256;          // 4 MiB

    const size_t base = (size_t)8192 * 256 * 2 * 3;        // 12 MiB
    const size_t osz  = (size_t)8192 * 256 * 4;            // 8 MiB per group
    const size_t mlsz = (size_t)8192 * 2 * 4;              // 64 KiB per group

    int gshift = 3;
    for (; gshift > 0; --gshift)
        if (base + ((osz + mlsz) << gshift) <= ws_size) break;

    int ng = 1 << gshift;
    float* Opart; float* Mlp;
    if (base + ((osz + mlsz) << gshift) <= ws_size) {
        Opart = (float*)((char*)d_ws + base);
        Mlp   = (float*)((char*)d_ws + base + osz * (size_t)ng);
    } else {           // last-resort: ng==1 partial straight into out
        gshift = 0; ng = 1;
        Opart = out;
        Mlp   = (float*)((char*)d_ws + base);
    }

    const int n8 = 8192 * 256 / 8;
    cvt_bf16_kernel<<<n8 / 256, 256, 0, stream>>>(Q, Qb, 0.0625f, n8);
    cvt_bf16_kernel<<<n8 / 256, 256, 0, stream>>>(K, Kb, 1.0f, n8);
    transpose_v_kernel<<<dim3(128, 4), 256, 0, stream>>>(V, Vt);
    attn_kernel<<<dim3(32, ng), 512, 0, stream>>>(Qb, Kb, Vt, Opart, Mlp,
                                                  8192 / ng, gshift);
    merge_kernel<<<8192, 256, 0, stream>>>(Opart, Mlp, out, ng);
}

// Round 4
// 137.125 us; speedup vs baseline: 3.4968x; 1.0421x over previous
//
#include <hip/hip_runtime.h>
#include <hip/hip_bf16.h>
#include <hip/hip_fp16.h>

// ScaledDotProductAttention N=M=8192, DK=DV=256, fp32 io.
// R4: R3 structure + exp2-domain softmax, tree reductions, permlane32_swap,
// setprio around MFMA clusters, fp32-direct Q, fp16 normalized partials.

typedef __attribute__((ext_vector_type(16))) float floatx16;
typedef __attribute__((ext_vector_type(8)))  short short8;

union S8u { short8 v; unsigned short u[8]; };

#if __has_builtin(__builtin_amdgcn_exp2f)
#define EXP2F(x) __builtin_amdgcn_exp2f(x)
#else
#define EXP2F(x) exp2f(x)
#endif

__device__ __forceinline__ unsigned short f2bf(float f) {
    unsigned int u = __builtin_bit_cast(unsigned int, f);
    unsigned int r = u + 0x7fffu + ((u >> 16) & 1u);   // RNE
    return (unsigned short)(r >> 16);
}

__device__ __forceinline__ unsigned cvtpk_bf16(float lo, float hi) {
    unsigned r;
    asm("v_cvt_pk_bf16_f32 %0, %1, %2" : "=v"(r) : "v"(lo), "v"(hi));
    return r;
}

__device__ __forceinline__ void gload16(const void* g, void* l) {
    __builtin_amdgcn_global_load_lds(
        (const __attribute__((address_space(1))) unsigned int*)g,
        (__attribute__((address_space(3))) unsigned int*)l, 16, 0, 0);
}

// ---------------- conversion kernels ----------------

__global__ void cvt_bf16_kernel(const float* __restrict__ in,
                                unsigned short* __restrict__ out,
                                float scale, int n8) {
    int i = blockIdx.x * blockDim.x + threadIdx.x;
    if (i >= n8) return;
    const float4* p = reinterpret_cast<const float4*>(in) + (size_t)i * 2;
    float4 a = p[0], b = p[1];
    S8u r;
    r.u[0] = f2bf(a.x * scale); r.u[1] = f2bf(a.y * scale);
    r.u[2] = f2bf(a.z * scale); r.u[3] = f2bf(a.w * scale);
    r.u[4] = f2bf(b.x * scale); r.u[5] = f2bf(b.y * scale);
    r.u[6] = f2bf(b.z * scale); r.u[7] = f2bf(b.w * scale);
    *reinterpret_cast<short8*>(out + (size_t)i * 8) = r.v;
}

// V [8192][256] f32 -> Vt [256][8192] bf16
__global__ void transpose_v_kernel(const float* __restrict__ V,
                                   unsigned short* __restrict__ Vt) {
    __shared__ unsigned short T[64][72];
    const int kv0 = blockIdx.x * 64;
    const int v0  = blockIdx.y * 64;
    const int tid = threadIdx.x;           // 256
#pragma unroll
    for (int it = 0; it < 4; ++it) {
        int flat = it * 256 + tid;
        int r  = flat >> 4;
        int c4 = (flat & 15) * 4;
        float4 f = *reinterpret_cast<const float4*>(
            V + (size_t)(kv0 + r) * 256 + v0 + c4);
        T[c4 + 0][r] = f2bf(f.x);
        T[c4 + 1][r] = f2bf(f.y);
        T[c4 + 2][r] = f2bf(f.z);
        T[c4 + 3][r] = f2bf(f.w);
    }
    __syncthreads();
#pragma unroll
    for (int it = 0; it < 2; ++it) {
        int flat = it * 256 + tid;
        int r  = flat >> 3;
        int c8 = (flat & 7) * 8;
        short8 v8 = *reinterpret_cast<const short8*>(&T[r][c8]);
        *reinterpret_cast<short8*>(Vt + (size_t)(v0 + r) * 8192 + kv0 + c8) = v8;
    }
}

// ---------------- main attention kernel ----------------

__global__ __launch_bounds__(512, 2)
void attn_kernel(const float* __restrict__ Qf,            // [8192][256] fp32
                 const unsigned short* __restrict__ Kb,   // [8192][256] bf16
                 const unsigned short* __restrict__ VtG,  // [256][8192] bf16
                 __half* __restrict__ Opart,              // [NG][8192][256]
                 float* __restrict__ Ml,                  // [NG][8192][2]
                 int kv_span, int gshift) {
    // [buf][ K 32KB | Vt 32KB ]
    __shared__ __align__(16) unsigned char lds[2][65536];

    const int tid  = threadIdx.x;
    const int lane = tid & 63;
    const int w    = tid >> 6;     // 0..7
    const int l31  = lane & 31;
    const int h    = lane >> 5;    // 0/1

    const int ngm1 = (1 << gshift) - 1;
    const int id   = blockIdx.x + 32 * blockIdx.y;
    const int g    = id & ngm1;          // XCD-affine
    const int qblk = id >> gshift;
    const int kv_begin = g * kv_span;
    const int tiles = kv_span >> 6;
    const int q0 = qblk * 256 + w * 32;

    // Q as B-fragments, built from fp32 with scale log2(e)/16 (exp2 domain)
    const float qs = 0.09016844005556021f;   // 0.0625 * log2(e)
    short8 qf[16];
    {
        const float* qp = Qf + (size_t)(q0 + l31) * 256 + h * 8;
#pragma unroll
        for (int ds = 0; ds < 16; ++ds) {
            float4 f0 = *reinterpret_cast<const float4*>(qp + ds * 16);
            float4 f1 = *reinterpret_cast<const float4*>(qp + ds * 16 + 4);
            uint4 uu;
            uu.x = cvtpk_bf16(f0.x * qs, f0.y * qs);
            uu.y = cvtpk_bf16(f0.z * qs, f0.w * qs);
            uu.z = cvtpk_bf16(f1.x * qs, f1.y * qs);
            uu.w = cvtpk_bf16(f1.z * qs, f1.w * qs);
            qf[ds] = __builtin_bit_cast(short8, uu);
        }
    }

    floatx16 o[8];
#pragma unroll
    for (int vt = 0; vt < 8; ++vt)
#pragma unroll
        for (int r = 0; r < 16; ++r) o[vt][r] = 0.f;
    float m_run = -1e30f, l_run = 0.f;

    // hoisted staging offsets (elements)
    int offk[4], offv[4];
#pragma unroll
    for (int i = 0; i < 4; ++i) {
        int j  = w * 4 + i;
        int rk = j * 2 + (lane >> 5);
        int ck = (lane & 31) ^ (rk & 7);
        offk[i] = rk * 256 + ck * 8;
        int rv = j * 8 + (lane >> 3);
        int cv = (lane & 7) ^ (rv & 7);
        offv[i] = rv * 8192 + cv * 8;
    }

    auto STAGE = [&](int kv0, int bufsel) {
        unsigned char* kb = &lds[bufsel][0];
        unsigned char* vb = &lds[bufsel][32768];
        const unsigned short* ks = Kb + (size_t)kv0 * 256;
        const unsigned short* vs = VtG + kv0;
#pragma unroll
        for (int i = 0; i < 4; ++i) {
            int j = w * 4 + i;
            gload16(ks + offk[i], kb + j * 1024);
            gload16(vs + offv[i], vb + j * 1024);
        }
    };

    STAGE(kv_begin, 0);
    asm volatile("s_waitcnt vmcnt(0)" ::: "memory");
    __syncthreads();

    const int swz = l31 & 7;

    for (int t = 0; t < tiles; ++t) {
        const int cur = t & 1;
        if (t + 1 < tiles) STAGE(kv_begin + (t + 1) * 64, cur ^ 1);

        const unsigned char* kl = &lds[cur][0];
        const unsigned char* vl = &lds[cur][32768];

        // ---- S^T = K x Q^T (log2 domain) ----
        floatx16 s0, s1;
#pragma unroll
        for (int r = 0; r < 16; ++r) { s0[r] = 0.f; s1[r] = 0.f; }
        __builtin_amdgcn_s_setprio(1);
#pragma unroll
        for (int ds = 0; ds < 16; ++ds) {
            int c0 = (ds * 2 + h) ^ swz;
            short8 a0 = *reinterpret_cast<const short8*>(kl + (size_t)l31 * 512 + c0 * 16);
            short8 a1 = *reinterpret_cast<const short8*>(kl + (size_t)(l31 + 32) * 512 + c0 * 16);
            s0 = __builtin_amdgcn_mfma_f32_32x32x16_bf16(a0, qf[ds], s0, 0, 0, 0);
            s1 = __builtin_amdgcn_mfma_f32_32x32x16_bf16(a1, qf[ds], s1, 0, 0, 0);
        }
        __builtin_amdgcn_s_setprio(0);

        // ---- online softmax, exp2 domain, tree reductions ----
        float t8[8];
#pragma unroll
        for (int i = 0; i < 8; ++i)
            t8[i] = fmaxf(fmaxf(s0[i], s0[i + 8]), fmaxf(s1[i], s1[i + 8]));
        float a0m = fmaxf(t8[0], t8[1]), a1m = fmaxf(t8[2], t8[3]);
        float a2m = fmaxf(t8[4], t8[5]), a3m = fmaxf(t8[6], t8[7]);
        float mt = fmaxf(fmaxf(a0m, a1m), fmaxf(a2m, a3m));
        mt = fmaxf(mt, __shfl_xor(mt, 32));
        if (__any(mt > m_run + 11.5f)) {         // defer-max (log2 units)
            float mnew = fmaxf(m_run, mt);
            float al = EXP2F(m_run - mnew);
            m_run = mnew;
            l_run *= al;
#pragma unroll
            for (int reg = 0; reg < 16; ++reg) {
                int srcl = ((reg & 3) + 8 * (reg >> 2)) + 4 * h;
                float alr = __shfl(al, srcl);
#pragma unroll
                for (int vt = 0; vt < 8; ++vt) o[vt][reg] *= alr;
            }
        }
#pragma unroll
        for (int r = 0; r < 16; ++r) s0[r] = EXP2F(s0[r] - m_run);
#pragma unroll
        for (int r = 0; r < 16; ++r) s1[r] = EXP2F(s1[r] - m_run);
        float u[8];
#pragma unroll
        for (int i = 0; i < 8; ++i)
            u[i] = (s0[i] + s0[i + 8]) + (s1[i] + s1[i + 8]);
        float lt = ((u[0] + u[1]) + (u[2] + u[3])) + ((u[4] + u[5]) + (u[6] + u[7]));
        lt += __shfl_xor(lt, 32);
        l_run += lt;

        // ---- PV ----
        auto buildPA = [&](const floatx16& sv, int rbase) -> short8 {
            unsigned cpk0 = cvtpk_bf16(sv[rbase + 0], sv[rbase + 1]);
            unsigned cpk1 = cvtpk_bf16(sv[rbase + 2], sv[rbase + 3]);
            unsigned cpk2 = cvtpk_bf16(sv[rbase + 4], sv[rbase + 5]);
            unsigned cpk3 = cvtpk_bf16(sv[rbase + 6], sv[rbase + 7]);
            uint4 uu;
#if __has_builtin(__builtin_amdgcn_permlane32_swap)
            auto r02 = __builtin_amdgcn_permlane32_swap((int)cpk0, (int)cpk2, false, false);
            auto r13 = __builtin_amdgcn_permlane32_swap((int)cpk1, (int)cpk3, false, false);
            uu.x = (unsigned)r02[0]; uu.y = (unsigned)r13[0];
            uu.z = (unsigned)r02[1]; uu.w = (unsigned)r13[1];
#else
            unsigned send0 = h ? cpk0 : cpk2;
            unsigned send1 = h ? cpk1 : cpk3;
            unsigned r0 = (unsigned)__shfl_xor((int)send0, 32);
            unsigned r1 = (unsigned)__shfl_xor((int)send1, 32);
            uu.x = h ? r0 : cpk0;
            uu.y = h ? r1 : cpk1;
            uu.z = h ? cpk2 : r0;
            uu.w = h ? cpk3 : r1;
#endif
            return __builtin_bit_cast(short8, uu);
        };

        __builtin_amdgcn_s_setprio(1);
#pragma unroll
        for (int kk = 0; kk < 4; ++kk) {
            short8 pa = buildPA((kk < 2) ? s0 : s1, (kk & 1) * 8);
            int cv = (kk * 2 + h) ^ swz;
#pragma unroll
            for (int vt = 0; vt < 8; ++vt) {
                short8 b = *reinterpret_cast<const short8*>(
                    vl + (size_t)(vt * 32 + l31) * 128 + cv * 16);
                o[vt] = __builtin_amdgcn_mfma_f32_32x32x16_bf16(pa, b, o[vt], 0, 0, 0);
            }
        }
        __builtin_amdgcn_s_setprio(0);

        asm volatile("s_waitcnt vmcnt(0)" ::: "memory");
        __syncthreads();
    }

    // ---- epilogue: normalized fp16 partial + (m,l) fp32 ----
    const size_t gq = (size_t)g * 8192;
    float linv = 1.0f / l_run;
#pragma unroll
    for (int reg = 0; reg < 16; ++reg) {
        int row = (reg & 3) + 8 * (reg >> 2) + 4 * h;
        float li = __shfl(linv, row);
#pragma unroll
        for (int vt = 0; vt < 8; ++vt)
            Opart[(gq + q0 + row) * 256 + vt * 32 + l31] =
                __float2half_rn(o[vt][reg] * li);
    }
    if (h == 0) {
        size_t idx = (gq + q0 + l31) * 2;
        Ml[idx]     = m_run;   // log2 domain
        Ml[idx + 1] = l_run;
    }
}

// ---------------- merge kernel ----------------

__global__ void merge_kernel(const __half* __restrict__ Opart,
                             const float* __restrict__ Ml,
                             float* __restrict__ out, int ngroups) {
    int row = blockIdx.x;
    int col = threadIdx.x;
    float m = -1e30f;
    for (int g = 0; g < ngroups; ++g)
        m = fmaxf(m, Ml[((size_t)g * 8192 + row) * 2]);
    float den = 0.f, acc = 0.f;
    for (int g = 0; g < ngroups; ++g) {
        float wg = EXP2F(Ml[((size_t)g * 8192 + row) * 2] - m) *
                   Ml[((size_t)g * 8192 + row) * 2 + 1];
        den += wg;
        acc += wg * __half2float(Opart[((size_t)g * 8192 + row) * 256 + col]);
    }
    out[(size_t)row * 256 + col] = acc / den;
}

// ---------------- launcher ----------------

extern "C" void kernel_launch(void* const* d_in, const int* in_sizes, int n_in,
                              void* d_out, int out_size, void* d_ws, size_t ws_size,
                              hipStream_t stream) {
    const float* Q = (const float*)d_in[0];
    const float* K = (const float*)d_in[1];
    const float* V = (const float*)d_in[2];
    float* out = (float*)d_out;

    unsigned short* Kb = (unsigned short*)d_ws;            // 4 MiB
    unsigned short* Vt = Kb + (size_t)8192 * 256;          // 4 MiB

    const size_t base = (size_t)8192 * 256 * 2 * 2;        // 8 MiB
    const size_t osz  = (size_t)8192 * 256 * 2;            // 4 MiB/group (fp16)
    const size_t mlsz = (size_t)8192 * 2 * 4;              // 64 KiB/group

    int gshift = 3;
    for (; gshift > 0; --gshift)
        if (base + ((osz + mlsz) << gshift) <= ws_size) break;
    int ng = 1 << gshift;

    __half* Opart = (__half*)((char*)d_ws + base);
    float*  Mlp   = (float*)((char*)d_ws + base + osz * (size_t)ng);

    const int n8 = 8192 * 256 / 8;
    cvt_bf16_kernel<<<n8 / 256, 256, 0, stream>>>(K, Kb, 1.0f, n8);
    transpose_v_kernel<<<dim3(128, 4), 256, 0, stream>>>(V, Vt);
    attn_kernel<<<dim3(32, ng), 512, 0, stream>>>(Q, Kb, Vt, Opart, Mlp,
                                                  8192 / ng, gshift);
    merge_kernel<<<8192, 256, 0, stream>>>(Opart, Mlp, out, ng);
}